// Round 5
// baseline (522.486 us; speedup 1.0000x reference)
//
#include <hip/hip_runtime.h>
#include <hip/hip_bf16.h>
#include <cstdint>
#include <cstddef>

#define N_NODES 65536
#define IN_FEAT 512
#define OUT_FEAT 256
#define N_REL 3
#define TOT_EDGES (N_REL * 500000)
#define N_EDGES 500000
#define NEG_SLOPE 0.2f
#define EPS_F 1e-9f
#define BK 32   // K-step for the double-buffered GEMM

typedef __bf16 bf16x8 __attribute__((ext_vector_type(8)));
typedef float f32x4 __attribute__((ext_vector_type(4)));

__device__ __forceinline__ void async16(const void* g, void* l) {
    __builtin_amdgcn_global_load_lds(
        (const __attribute__((address_space(1))) unsigned int*)g,
        (__attribute__((address_space(3))) unsigned int*)l, 16, 0, 0);
}

// ---------- fused prep: el/er/head init + W transpose ----------
// Roles by blockIdx.x (block-uniform branch -> __syncthreads safe):
//   [0, 768)   : init el=er=0, head=-1   (768*256 = 196608)
//   [768, 864) : Wt transpose (96 blocks)
__global__ __launch_bounds__(256) void kPrep(
    const float* __restrict__ W,
    __bf16* __restrict__ Wt,
    float* __restrict__ el, float* __restrict__ er, int* __restrict__ head) {
    __shared__ float tile[64][65];
    const int b = blockIdx.x;
    const int t = threadIdx.x;
    if (b < 768) {
        int i = b * 256 + t;
        el[i] = 0.f;
        er[i] = 0.f;
        head[i] = -1;
    } else {
        int b2 = b - 768;              // r*32 + kt*4 + nt
        int r = b2 >> 5;
        int kt = (b2 >> 2) & 7;
        int nt = b2 & 3;
        int k0 = kt * 64, n0 = nt * 64;
        int trow = t >> 6, tcol = t & 63;
        const float* Wr = W + (size_t)r * IN_FEAT * OUT_FEAT;
#pragma unroll
        for (int p = 0; p < 16; p++) {
            int k = p * 4 + trow;
            tile[k][tcol] = Wr[(size_t)(k0 + k) * OUT_FEAT + n0 + tcol];
        }
        __syncthreads();
        __bf16* Wtr = Wt + (size_t)r * OUT_FEAT * IN_FEAT;
#pragma unroll
        for (int p = 0; p < 16; p++) {
            int n = p * 4 + trow;
            Wtr[(size_t)(n0 + n) * IN_FEAT + k0 + tcol] = (__bf16)tile[tcol][n];
        }
    }
}

// ---------- GEMM: 256x256xBK32 double-buffered 2-phase pipeline ----------
// T3-minimum structure (guide §5.5): prologue-stage buf0; per step: issue
// stage(next) FIRST (B via global_load_lds, A via fp32 reg-loads), then
// compute(cur) (ds_read + 32 MFMA/wave), then cvt+ds_write A(next), then ONE
// barrier (compiler's pre-barrier vmcnt/lgkm drain covers both buffers'
// staging). Staging latency hides under compute -- vs the old serial
// stage/barrier/compute/barrier which exposed it every K-step.
// 512 thr = 8 waves (2m x 4n), wave tile 128x64, acc[8][4].
// LDS 64 KB: 2 buf x (A 16K + B 16K). 1 block/CU (VGPR-bound), 2 waves/SIMD.
// XCD mapping: bid&7 = XCD; slot runs r-fastest so the 3 rels of one m-tile
// are dispatch-adjacent on the same XCD (A-panel fetched once, L2-hit twice).
__global__ __launch_bounds__(512, 2) void kGemm(
    const float* __restrict__ h, const __bf16* __restrict__ Wt,
    const float* __restrict__ attn_l, const float* __restrict__ attn_r,
    __bf16* __restrict__ z, float* __restrict__ el, float* __restrict__ er) {
    __shared__ __bf16 Al[2][256 * BK];   // 2 x 16 KB
    __shared__ __bf16 Bl[2][256 * BK];   // 2 x 16 KB

    const int bid = blockIdx.x;
    const int xcd = bid & 7;
    const int slot = bid >> 3;        // 0..95
    const int mtg = slot / 3;         // 0..31
    const int r = slot - mtg * 3;
    const int m_base = (xcd * 32 + mtg) * 256;

    const int t = threadIdx.x;
    const int lane = t & 63;
    const int wave = t >> 6;          // 0..7
    const int wm = wave >> 2;         // 0..1  (128-row half)
    const int wn = wave & 3;          // 0..3  (64-col quarter)
    const int colL = lane & 15, quad = lane >> 4;

    const __bf16* WtR = Wt + (size_t)r * OUT_FEAT * IN_FEAT;

    f32x4 acc[8][4];
#pragma unroll
    for (int mt = 0; mt < 8; mt++)
#pragma unroll
        for (int nt = 0; nt < 4; nt++) acc[mt][nt] = (f32x4){0.f, 0.f, 0.f, 0.f};

    // ---- staging helpers (inlined per use) ----
    // chunk id s in [0,1024): row = s>>2, cp = s&3; LDS slot (row,cp) holds
    // global chunk cp^(row&3)  (XOR swizzle -> 2-way-free ds_read pattern).

    // prologue: stage k0=0 into buffer 0
    {
#pragma unroll
        for (int i = 0; i < 2; i++) {          // B: global_load_lds
            int s = i * 512 + t;
            int n = s >> 2, cp = s & 3, cs = cp ^ (n & 3);
            const __bf16* g = WtR + (size_t)n * IN_FEAT + cs * 8;
            async16(g, (__bf16*)Bl[0] + (size_t)s * 8);
        }
#pragma unroll
        for (int i = 0; i < 2; i++) {          // A: fp32 -> cvt -> ds_write
            int s = i * 512 + t;
            int row = s >> 2, cp = s & 3, cs = cp ^ (row & 3);
            const float* g = h + (size_t)(m_base + row) * IN_FEAT + cs * 8;
            float4 v0 = ((const float4*)g)[0];
            float4 v1 = ((const float4*)g)[1];
            bf16x8 w;
            w[0] = (__bf16)v0.x; w[1] = (__bf16)v0.y; w[2] = (__bf16)v0.z; w[3] = (__bf16)v0.w;
            w[4] = (__bf16)v1.x; w[5] = (__bf16)v1.y; w[6] = (__bf16)v1.z; w[7] = (__bf16)v1.w;
            *(bf16x8*)((__bf16*)Al[0] + (size_t)s * 8) = w;
        }
    }
    __syncthreads();   // drains vmcnt (gload_lds) + lgkm (ds_write)

    const int NSTEP = IN_FEAT / BK;   // 16
    for (int step = 0; step < NSTEP; ++step) {
        const int cur = step & 1, nxt = cur ^ 1;
        const int k1 = (step + 1) * BK;
        float4 a0[2], a1[2];
        const bool more = (step + 1) < NSTEP;
        if (more) {
            // issue next-tile staging loads BEFORE compute (overlap)
#pragma unroll
            for (int i = 0; i < 2; i++) {      // B -> LDS direct
                int s = i * 512 + t;
                int n = s >> 2, cp = s & 3, cs = cp ^ (n & 3);
                const __bf16* g = WtR + (size_t)n * IN_FEAT + k1 + cs * 8;
                async16(g, (__bf16*)Bl[nxt] + (size_t)s * 8);
            }
#pragma unroll
            for (int i = 0; i < 2; i++) {      // A -> regs (consume after compute)
                int s = i * 512 + t;
                int row = s >> 2, cp = s & 3, cs = cp ^ (row & 3);
                const float* g = h + (size_t)(m_base + row) * IN_FEAT + k1 + cs * 8;
                a0[i] = ((const float4*)g)[0];
                a1[i] = ((const float4*)g)[1];
            }
        }
        // compute current buffer: 12 ds_read_b128 + 32 MFMA per wave
        {
            const __bf16* Ab = (const __bf16*)Al[cur];
            const __bf16* Bb = (const __bf16*)Bl[cur];
            bf16x8 af[8], bfr[4];
#pragma unroll
            for (int mt = 0; mt < 8; mt++) {
                int row = wm * 128 + mt * 16 + colL;
                int cp = quad ^ (row & 3);
                af[mt] = *(const bf16x8*)(Ab + (size_t)((row << 2) + cp) * 8);
            }
#pragma unroll
            for (int nt = 0; nt < 4; nt++) {
                int n = wn * 64 + nt * 16 + colL;
                int cp = quad ^ (n & 3);
                bfr[nt] = *(const bf16x8*)(Bb + (size_t)((n << 2) + cp) * 8);
            }
#pragma unroll
            for (int mt = 0; mt < 8; mt++)
#pragma unroll
                for (int nt = 0; nt < 4; nt++)
                    acc[mt][nt] = __builtin_amdgcn_mfma_f32_16x16x32_bf16(
                        af[mt], bfr[nt], acc[mt][nt], 0, 0, 0);
        }
        if (more) {
            // convert + write A(next) after compute (loads have landed by now)
#pragma unroll
            for (int i = 0; i < 2; i++) {
                int s = i * 512 + t;
                bf16x8 w;
                w[0] = (__bf16)a0[i].x; w[1] = (__bf16)a0[i].y;
                w[2] = (__bf16)a0[i].z; w[3] = (__bf16)a0[i].w;
                w[4] = (__bf16)a1[i].x; w[5] = (__bf16)a1[i].y;
                w[6] = (__bf16)a1[i].z; w[7] = (__bf16)a1[i].w;
                *(bf16x8*)((__bf16*)Al[nxt] + (size_t)s * 8) = w;
            }
        }
        __syncthreads();   // next buffer fully staged for everyone
    }

    // epilogue: z write + el/er partial dot + wave reduce + atomic
    const float* alv = attn_l + r * OUT_FEAT;
    const float* arv = attn_r + r * OUT_FEAT;
    __bf16* zr = z + (size_t)r * N_NODES * OUT_FEAT;
    float elp[8][4], erp[8][4];
#pragma unroll
    for (int mt = 0; mt < 8; mt++)
#pragma unroll
        for (int q = 0; q < 4; q++) { elp[mt][q] = 0.f; erp[mt][q] = 0.f; }
#pragma unroll
    for (int mt = 0; mt < 8; mt++) {
#pragma unroll
        for (int nt = 0; nt < 4; nt++) {
            int c = wn * 64 + nt * 16 + colL;
            float al = alv[c], ar = arv[c];
#pragma unroll
            for (int q = 0; q < 4; q++) {
                float v = acc[mt][nt][q];
                int row = m_base + wm * 128 + mt * 16 + quad * 4 + q;
                zr[(size_t)row * OUT_FEAT + c] = (__bf16)v;
                elp[mt][q] += v * al;
                erp[mt][q] += v * ar;
            }
        }
    }
#pragma unroll
    for (int mt = 0; mt < 8; mt++)
#pragma unroll
        for (int q = 0; q < 4; q++) {
#pragma unroll
            for (int off = 1; off < 16; off <<= 1) {
                elp[mt][q] += __shfl_xor(elp[mt][q], off, 64);
                erp[mt][q] += __shfl_xor(erp[mt][q], off, 64);
            }
        }
    if (colL == 0) {
#pragma unroll
        for (int mt = 0; mt < 8; mt++)
#pragma unroll
            for (int q = 0; q < 4; q++) {
                int row = m_base + wm * 128 + mt * 16 + quad * 4 + q;
                atomicAdd(el + r * N_NODES + row, elp[mt][q]);
                atomicAdd(er + r * N_NODES + row, erp[mt][q]);
            }
    }
}

// ---------- edge bucketing: per-(rel,dst) linked list; next2[e] = {next, src[e]} ----------
__global__ void kLink(const int* __restrict__ dst, const int* __restrict__ srcArr,
                      int* __restrict__ head, int2* __restrict__ next2) {
    int i = blockIdx.x * blockDim.x + threadIdx.x;
    if (i >= TOT_EDGES) return;
    int r = i / N_EDGES;
    int d = dst[i];
    int prev = atomicExch(head + r * N_NODES + d, i);
    next2[i] = make_int2(prev, srcArr[i]);
}

// ---------- aggregation: one half-wave per (node, rel) chain ----------
// [FROZEN control — measured best form, R1. Two MLP-doubling probes (R1,R4)
// both null -> fabric-throughput-bound at ~3.5 TB/s for this random-512B
// gather; ~165 us is this formulation's roofline.]
__global__ __launch_bounds__(192) void kAgg(
    const __bf16* __restrict__ z, const int* __restrict__ head,
    const int2* __restrict__ next2,
    const float* __restrict__ el, const float* __restrict__ er,
    const float* __restrict__ bias, float* __restrict__ out) {
    __shared__ float cm[6][256];
    const int t = threadIdx.x;
    const int wv = t >> 6;
    const int lane = t & 63;
    const int half = lane >> 5;
    const int l = lane & 31;
    const int hw = wv * 2 + half;        // 0..5
    const int nl = (hw >= 3) ? 1 : 0;    // node_local
    const int r = hw - nl * 3;           // relation
    const int node = blockIdx.x * 2 + nl;
    const int idx = r * N_NODES + node;

    const float erv = er[idx];
    const float* elr = el + r * N_NODES;
    const uint4* zrel = (const uint4*)(z + (size_t)r * N_NODES * OUT_FEAT);

    float p0 = 0.f, p1 = 0.f, p2 = 0.f, p3 = 0.f;
    float p4 = 0.f, p5 = 0.f, p6 = 0.f, p7 = 0.f;
    float wsum = 0.f;
    int cur = head[idx];
    while (cur >= 0) {
        int2 ns = next2[cur];            // {next edge, src node}
        int s = ns.y;
        float x = elr[s] + erv;
        x = x > 0.f ? x : NEG_SLOPE * x;
        float w = __expf(x);
        uint4 v = zrel[(size_t)s * 32 + l];
        wsum += w;
        p0 += w * __uint_as_float(v.x << 16);
        p1 += w * __uint_as_float(v.x & 0xFFFF0000u);
        p2 += w * __uint_as_float(v.y << 16);
        p3 += w * __uint_as_float(v.y & 0xFFFF0000u);
        p4 += w * __uint_as_float(v.z << 16);
        p5 += w * __uint_as_float(v.z & 0xFFFF0000u);
        p6 += w * __uint_as_float(v.w << 16);
        p7 += w * __uint_as_float(v.w & 0xFFFF0000u);
        cur = ns.x;
    }
    float invd = 1.f / (wsum + EPS_F);
    float* cr = &cm[hw][l * 8];
    *(float4*)cr       = make_float4(p0 * invd, p1 * invd, p2 * invd, p3 * invd);
    *(float4*)(cr + 4) = make_float4(p4 * invd, p5 * invd, p6 * invd, p7 * invd);
    __syncthreads();

    if (r == 0) {   // half-waves 0 and 3 combine their node's 3 rel-partials
        const int c = l * 8;
        const float* r0 = &cm[nl * 3 + 0][c];
        const float* r1 = &cm[nl * 3 + 1][c];
        const float* r2 = &cm[nl * 3 + 2][c];
        const float* b0 = bias + c;
        const float* b1 = bias + OUT_FEAT + c;
        const float* b2 = bias + 2 * OUT_FEAT + c;
        float f0 = r0[0] + r1[0] + r2[0] + b0[0] + b1[0] + b2[0];
        float f1 = r0[1] + r1[1] + r2[1] + b0[1] + b1[1] + b2[1];
        float f2 = r0[2] + r1[2] + r2[2] + b0[2] + b1[2] + b2[2];
        float f3 = r0[3] + r1[3] + r2[3] + b0[3] + b1[3] + b2[3];
        float f4 = r0[4] + r1[4] + r2[4] + b0[4] + b1[4] + b2[4];
        float f5 = r0[5] + r1[5] + r2[5] + b0[5] + b1[5] + b2[5];
        float f6 = r0[6] + r1[6] + r2[6] + b0[6] + b1[6] + b2[6];
        float f7 = r0[7] + r1[7] + r2[7] + b0[7] + b1[7] + b2[7];
        float* orow = out + (size_t)node * OUT_FEAT + c;
        *(float4*)orow       = make_float4(f0, f1, f2, f3);
        *(float4*)(orow + 4) = make_float4(f4, f5, f6, f7);
    }
}

extern "C" void kernel_launch(void* const* d_in, const int* in_sizes, int n_in,
                              void* d_out, int out_size, void* d_ws, size_t ws_size,
                              hipStream_t stream) {
    const float* h      = (const float*)d_in[0];
    const float* W      = (const float*)d_in[1];
    const float* attn_l = (const float*)d_in[2];
    const float* attn_r = (const float*)d_in[3];
    const float* bias   = (const float*)d_in[4];
    const int*   src    = (const int*)d_in[5];
    const int*   dst    = (const int*)d_in[6];
    float* out = (float*)d_out;
    char* ws = (char*)d_ws;

    // static workspace layout (constant across calls -> capture-safe)
    size_t off_b = 0;
    auto alloc = [&](size_t bytes) {
        size_t o = off_b;
        off_b = (off_b + bytes + 255) & ~(size_t)255;
        return o;
    };
    size_t oZ    = alloc((size_t)N_REL * N_NODES * OUT_FEAT * 2);
    size_t oWT   = alloc((size_t)N_REL * OUT_FEAT * IN_FEAT * 2);
    size_t oEL   = alloc((size_t)N_REL * N_NODES * 4);
    size_t oER   = alloc((size_t)N_REL * N_NODES * 4);
    size_t oHEAD = alloc((size_t)N_REL * N_NODES * 4);
    size_t oNEXT = alloc((size_t)TOT_EDGES * 8);   // int2 {next, src}

    __bf16* z     = (__bf16*)(ws + oZ);
    __bf16* Wt    = (__bf16*)(ws + oWT);
    float*  el    = (float*)(ws + oEL);
    float*  er    = (float*)(ws + oER);
    int*    head  = (int*)(ws + oHEAD);
    int2*   next2 = (int2*)(ws + oNEXT);

    kPrep<<<864, 256, 0, stream>>>(W, Wt, el, er, head);
    kLink<<<(TOT_EDGES + 255) / 256, 256, 0, stream>>>(dst, src, head, next2);
    kGemm<<<768, 512, 0, stream>>>(h, Wt, attn_l, attn_r, z, el, er);
    kAgg<<<N_NODES / 2, 192, 0, stream>>>(z, head, next2, el, er, bias, out);
}

// Round 6
// 476.275 us; speedup vs baseline: 1.0970x; 1.0970x over previous
//
#include <hip/hip_runtime.h>
#include <hip/hip_bf16.h>
#include <cstdint>
#include <cstddef>

#define N_NODES 65536
#define IN_FEAT 512
#define OUT_FEAT 256
#define N_REL 3
#define TOT_EDGES (N_REL * 500000)
#define N_EDGES 500000
#define NEG_SLOPE 0.2f
#define EPS_F 1e-9f
#define BK 64

#define NB_GEMM 1536
#define NB_LINK ((TOT_EDGES + 255) / 256)   // 5860

typedef __bf16 bf16x8 __attribute__((ext_vector_type(8)));
typedef float f32x4 __attribute__((ext_vector_type(4)));

__device__ __forceinline__ void async16(const void* g, void* l) {
    __builtin_amdgcn_global_load_lds(
        (const __attribute__((address_space(1))) unsigned int*)g,
        (__attribute__((address_space(3))) unsigned int*)l, 16, 0, 0);
}

// ---------- fused prep: el/er/head init + W transpose ----------
// Roles by blockIdx.x (block-uniform branch -> __syncthreads safe):
//   [0, 768)   : init el=er=0, head=-1   (768*256 = 196608)
//   [768, 864) : Wt transpose (96 blocks)
__global__ __launch_bounds__(256) void kPrep(
    const float* __restrict__ W,
    __bf16* __restrict__ Wt,
    float* __restrict__ el, float* __restrict__ er, int* __restrict__ head) {
    __shared__ float tile[64][65];
    const int b = blockIdx.x;
    const int t = threadIdx.x;
    if (b < 768) {
        int i = b * 256 + t;
        el[i] = 0.f;
        er[i] = 0.f;
        head[i] = -1;
    } else {
        int b2 = b - 768;              // r*32 + kt*4 + nt
        int r = b2 >> 5;
        int kt = (b2 >> 2) & 7;
        int nt = b2 & 3;
        int k0 = kt * 64, n0 = nt * 64;
        int trow = t >> 6, tcol = t & 63;
        const float* Wr = W + (size_t)r * IN_FEAT * OUT_FEAT;
#pragma unroll
        for (int p = 0; p < 16; p++) {
            int k = p * 4 + trow;
            tile[k][tcol] = Wr[(size_t)(k0 + k) * OUT_FEAT + n0 + tcol];
        }
        __syncthreads();
        __bf16* Wtr = Wt + (size_t)r * OUT_FEAT * IN_FEAT;
#pragma unroll
        for (int p = 0; p < 16; p++) {
            int n = p * 4 + trow;
            Wtr[(size_t)(n0 + n) * IN_FEAT + k0 + tcol] = (__bf16)tile[tcol][n];
        }
    }
}

// ---------- fused GEMM + edge-link: role by blockIdx ----------
// blocks [0, NB_GEMM): R4-exact GEMM 128x256xBK64, 2 blocks/CU (LDS 48 KB).
// blocks [NB_GEMM, NB_GEMM+NB_LINK): linked-list build, 1 edge/thread.
// The two roles touch disjoint buffers (z/el/er vs head/next2) and both
// depend only on kPrep -> safe in one dispatch. GEMM blocks dispatch first
// and saturate the CUs; link blocks (memory/atomic-bound, no MFMA) fill the
// remaining wave slots (48KB x 3 = 144KB <= 160KB admits 2 GEMM + 1 link
// block per CU) -> kLink's standalone ~dozens of us hides under MFMA.
__global__ __launch_bounds__(256, 2) void kGemmLink(
    const float* __restrict__ h, const __bf16* __restrict__ Wt,
    const float* __restrict__ attn_l, const float* __restrict__ attn_r,
    __bf16* __restrict__ z, float* __restrict__ el, float* __restrict__ er,
    const int* __restrict__ dst, const int* __restrict__ srcArr,
    int* __restrict__ head, int2* __restrict__ next2) {
    __shared__ __bf16 Al[128 * BK];   // 16 KB
    __shared__ __bf16 Bl[256 * BK];   // 32 KB
    const int bid = blockIdx.x;
    const int t = threadIdx.x;

    if (bid >= NB_GEMM) {
        // ---- link role ----
        int i = (bid - NB_GEMM) * 256 + t;
        if (i < TOT_EDGES) {
            int r = i / N_EDGES;
            int d = dst[i];
            int prev = atomicExch(head + r * N_NODES + d, i);
            next2[i] = make_int2(prev, srcArr[i]);
        }
        return;
    }

    // ---- GEMM role (R4-verified form) ----
    // XCD mapping: bid&7 = XCD; slot runs r-fastest so the 3 rels of one
    // m-tile are dispatch-adjacent on the same XCD (A-panel HBM-fetched once).
    const int xcd = bid & 7;
    const int slot = bid >> 3;        // 0..191
    const int mt6 = slot / 3;         // 0..63
    const int r = slot - mt6 * 3;
    const int m_base = (xcd * 64 + mt6) * 128;

    const int lane = t & 63;
    const int wave = t >> 6;
    const int wm = wave >> 1, wn = wave & 1;
    const int colL = lane & 15, quad = lane >> 4;

    const __bf16* WtR = Wt + (size_t)r * OUT_FEAT * IN_FEAT;

    f32x4 acc[4][8];
#pragma unroll
    for (int mt = 0; mt < 4; mt++)
#pragma unroll
        for (int nt = 0; nt < 8; nt++) acc[mt][nt] = (f32x4){0.f, 0.f, 0.f, 0.f};

    for (int k0 = 0; k0 < IN_FEAT; k0 += BK) {
        if (k0) __syncthreads();
        // B: 2048 chunks via global_load_lds
#pragma unroll
        for (int i = 0; i < 8; i++) {
            int s = i * 256 + t;
            int n = s >> 3, cp = s & 7, cs = cp ^ (n & 7);
            const __bf16* g = WtR + (size_t)n * IN_FEAT + k0 + cs * 8;
            __bf16* l = Bl + (size_t)(i * 256 + (wave << 6)) * 8;
            async16(g, l);
        }
        // A: 1024 chunks, fp32 load + cvt + ds_write (swizzled source)
#pragma unroll
        for (int i = 0; i < 4; i++) {
            int s = i * 256 + t;
            int row = s >> 3, cp = s & 7, cs = cp ^ (row & 7);
            const float* g = h + (size_t)(m_base + row) * IN_FEAT + k0 + cs * 8;
            float4 v0 = ((const float4*)g)[0];
            float4 v1 = ((const float4*)g)[1];
            bf16x8 w;
            w[0] = (__bf16)v0.x; w[1] = (__bf16)v0.y; w[2] = (__bf16)v0.z; w[3] = (__bf16)v0.w;
            w[4] = (__bf16)v1.x; w[5] = (__bf16)v1.y; w[6] = (__bf16)v1.z; w[7] = (__bf16)v1.w;
            *(bf16x8*)(Al + (size_t)s * 8) = w;
        }
        __syncthreads();
#pragma unroll
        for (int kk = 0; kk < 2; kk++) {
            const int cbase = kk * 4 + quad;
            bf16x8 af[4], bfr[8];
#pragma unroll
            for (int mt = 0; mt < 4; mt++) {
                int row = wm * 64 + mt * 16 + colL;
                int cp = cbase ^ (row & 7);
                af[mt] = *(const bf16x8*)(Al + (size_t)((row << 3) + cp) * 8);
            }
#pragma unroll
            for (int nt = 0; nt < 8; nt++) {
                int n = wn * 128 + nt * 16 + colL;
                int cp = cbase ^ (n & 7);
                bfr[nt] = *(const bf16x8*)(Bl + (size_t)((n << 3) + cp) * 8);
            }
#pragma unroll
            for (int mt = 0; mt < 4; mt++)
#pragma unroll
                for (int nt = 0; nt < 8; nt++)
                    acc[mt][nt] = __builtin_amdgcn_mfma_f32_16x16x32_bf16(
                        af[mt], bfr[nt], acc[mt][nt], 0, 0, 0);
        }
    }

    // epilogue: z write + el/er partial dot + wave reduce + atomic
    const float* alv = attn_l + r * OUT_FEAT;
    const float* arv = attn_r + r * OUT_FEAT;
    __bf16* zr = z + (size_t)r * N_NODES * OUT_FEAT;
    float elp[4][4], erp[4][4];
#pragma unroll
    for (int mt = 0; mt < 4; mt++)
#pragma unroll
        for (int q = 0; q < 4; q++) { elp[mt][q] = 0.f; erp[mt][q] = 0.f; }
#pragma unroll
    for (int mt = 0; mt < 4; mt++) {
#pragma unroll
        for (int nt = 0; nt < 8; nt++) {
            int c = wn * 128 + nt * 16 + colL;
            float al = alv[c], ar = arv[c];
#pragma unroll
            for (int q = 0; q < 4; q++) {
                float v = acc[mt][nt][q];
                int row = m_base + wm * 64 + mt * 16 + quad * 4 + q;
                zr[(size_t)row * OUT_FEAT + c] = (__bf16)v;
                elp[mt][q] += v * al;
                erp[mt][q] += v * ar;
            }
        }
    }
#pragma unroll
    for (int mt = 0; mt < 4; mt++)
#pragma unroll
        for (int q = 0; q < 4; q++) {
#pragma unroll
            for (int off = 1; off < 16; off <<= 1) {
                elp[mt][q] += __shfl_xor(elp[mt][q], off, 64);
                erp[mt][q] += __shfl_xor(erp[mt][q], off, 64);
            }
        }
    if (colL == 0) {
#pragma unroll
        for (int mt = 0; mt < 4; mt++)
#pragma unroll
            for (int q = 0; q < 4; q++) {
                int row = m_base + wm * 64 + mt * 16 + quad * 4 + q;
                atomicAdd(el + r * N_NODES + row, elp[mt][q]);
                atomicAdd(er + r * N_NODES + row, erp[mt][q]);
            }
    }
}

// ---------- aggregation: one half-wave per (node, rel) chain ----------
// [FROZEN control — measured best form (R5: 159.5 us). Two MLP-doubling
// probes (R1,R4) both null -> fabric-throughput-bound at ~3.6 TB/s for this
// random-512B gather; ~160 us is this formulation's roofline.]
__global__ __launch_bounds__(192) void kAgg(
    const __bf16* __restrict__ z, const int* __restrict__ head,
    const int2* __restrict__ next2,
    const float* __restrict__ el, const float* __restrict__ er,
    const float* __restrict__ bias, float* __restrict__ out) {
    __shared__ float cm[6][256];
    const int t = threadIdx.x;
    const int wv = t >> 6;
    const int lane = t & 63;
    const int half = lane >> 5;
    const int l = lane & 31;
    const int hw = wv * 2 + half;        // 0..5
    const int nl = (hw >= 3) ? 1 : 0;    // node_local
    const int r = hw - nl * 3;           // relation
    const int node = blockIdx.x * 2 + nl;
    const int idx = r * N_NODES + node;

    const float erv = er[idx];
    const float* elr = el + r * N_NODES;
    const uint4* zrel = (const uint4*)(z + (size_t)r * N_NODES * OUT_FEAT);

    float p0 = 0.f, p1 = 0.f, p2 = 0.f, p3 = 0.f;
    float p4 = 0.f, p5 = 0.f, p6 = 0.f, p7 = 0.f;
    float wsum = 0.f;
    int cur = head[idx];
    while (cur >= 0) {
        int2 ns = next2[cur];            // {next edge, src node}
        int s = ns.y;
        float x = elr[s] + erv;
        x = x > 0.f ? x : NEG_SLOPE * x;
        float w = __expf(x);
        uint4 v = zrel[(size_t)s * 32 + l];
        wsum += w;
        p0 += w * __uint_as_float(v.x << 16);
        p1 += w * __uint_as_float(v.x & 0xFFFF0000u);
        p2 += w * __uint_as_float(v.y << 16);
        p3 += w * __uint_as_float(v.y & 0xFFFF0000u);
        p4 += w * __uint_as_float(v.z << 16);
        p5 += w * __uint_as_float(v.z & 0xFFFF0000u);
        p6 += w * __uint_as_float(v.w << 16);
        p7 += w * __uint_as_float(v.w & 0xFFFF0000u);
        cur = ns.x;
    }
    float invd = 1.f / (wsum + EPS_F);
    float* cr = &cm[hw][l * 8];
    *(float4*)cr       = make_float4(p0 * invd, p1 * invd, p2 * invd, p3 * invd);
    *(float4*)(cr + 4) = make_float4(p4 * invd, p5 * invd, p6 * invd, p7 * invd);
    __syncthreads();

    if (r == 0) {   // half-waves 0 and 3 combine their node's 3 rel-partials
        const int c = l * 8;
        const float* r0 = &cm[nl * 3 + 0][c];
        const float* r1 = &cm[nl * 3 + 1][c];
        const float* r2 = &cm[nl * 3 + 2][c];
        const float* b0 = bias + c;
        const float* b1 = bias + OUT_FEAT + c;
        const float* b2 = bias + 2 * OUT_FEAT + c;
        float f0 = r0[0] + r1[0] + r2[0] + b0[0] + b1[0] + b2[0];
        float f1 = r0[1] + r1[1] + r2[1] + b0[1] + b1[1] + b2[1];
        float f2 = r0[2] + r1[2] + r2[2] + b0[2] + b1[2] + b2[2];
        float f3 = r0[3] + r1[3] + r2[3] + b0[3] + b1[3] + b2[3];
        float f4 = r0[4] + r1[4] + r2[4] + b0[4] + b1[4] + b2[4];
        float f5 = r0[5] + r1[5] + r2[5] + b0[5] + b1[5] + b2[5];
        float f6 = r0[6] + r1[6] + r2[6] + b0[6] + b1[6] + b2[6];
        float f7 = r0[7] + r1[7] + r2[7] + b0[7] + b1[7] + b2[7];
        float* orow = out + (size_t)node * OUT_FEAT + c;
        *(float4*)orow       = make_float4(f0, f1, f2, f3);
        *(float4*)(orow + 4) = make_float4(f4, f5, f6, f7);
    }
}

extern "C" void kernel_launch(void* const* d_in, const int* in_sizes, int n_in,
                              void* d_out, int out_size, void* d_ws, size_t ws_size,
                              hipStream_t stream) {
    const float* h      = (const float*)d_in[0];
    const float* W      = (const float*)d_in[1];
    const float* attn_l = (const float*)d_in[2];
    const float* attn_r = (const float*)d_in[3];
    const float* bias   = (const float*)d_in[4];
    const int*   src    = (const int*)d_in[5];
    const int*   dst    = (const int*)d_in[6];
    float* out = (float*)d_out;
    char* ws = (char*)d_ws;

    // static workspace layout (constant across calls -> capture-safe)
    size_t off_b = 0;
    auto alloc = [&](size_t bytes) {
        size_t o = off_b;
        off_b = (off_b + bytes + 255) & ~(size_t)255;
        return o;
    };
    size_t oZ    = alloc((size_t)N_REL * N_NODES * OUT_FEAT * 2);
    size_t oWT   = alloc((size_t)N_REL * OUT_FEAT * IN_FEAT * 2);
    size_t oEL   = alloc((size_t)N_REL * N_NODES * 4);
    size_t oER   = alloc((size_t)N_REL * N_NODES * 4);
    size_t oHEAD = alloc((size_t)N_REL * N_NODES * 4);
    size_t oNEXT = alloc((size_t)TOT_EDGES * 8);   // int2 {next, src}

    __bf16* z     = (__bf16*)(ws + oZ);
    __bf16* Wt    = (__bf16*)(ws + oWT);
    float*  el    = (float*)(ws + oEL);
    float*  er    = (float*)(ws + oER);
    int*    head  = (int*)(ws + oHEAD);
    int2*   next2 = (int2*)(ws + oNEXT);

    kPrep<<<864, 256, 0, stream>>>(W, Wt, el, er, head);
    kGemmLink<<<NB_GEMM + NB_LINK, 256, 0, stream>>>(
        h, Wt, attn_l, attn_r, z, el, er, dst, src, head, next2);
    kAgg<<<N_NODES / 2, 192, 0, stream>>>(z, head, next2, el, er, bias, out);
}